// Round 1
// baseline (102.676 us; speedup 1.0000x reference)
//
#include <hip/hip_runtime.h>
#include <hip/hip_bf16.h>

#define NB 4
#define NH 12
#define SEQ 4096
#define DIM 64

typedef __attribute__((ext_vector_type(8))) short short8;
typedef __attribute__((ext_vector_type(4))) float f32x4;
typedef __attribute__((ext_vector_type(4))) unsigned short ushort4v;

static __device__ __forceinline__ unsigned short f2bf(float f) {
    unsigned int u = __builtin_bit_cast(unsigned int, f);
    u = u + 0x7FFFu + ((u >> 16) & 1u);   // round-to-nearest-even (inputs are finite)
    return (unsigned short)(u >> 16);
}

__global__ __launch_bounds__(512, 2)
void blk_attn(const float* __restrict__ Q, const float* __restrict__ K,
              const float* __restrict__ V, const float* __restrict__ M,
              float* __restrict__ O) {
    // XCD-aware swizzle: 1536 blocks, 1536 % 8 == 0 -> bijective
    int bid = blockIdx.x;
    bid = (bid & 7) * 192 + (bid >> 3);

    const int j  = bid & 31;   // 128-row query group
    const int bh = bid >> 5;   // b*NH + h
    const int b  = bh / NH;

    const size_t base = (size_t)bh * SEQ * DIM;
    const float* Qp = Q + base + (size_t)j * 128 * DIM;
    const float* Kp = K + base;
    const float* Vp = V + base;
    const float* Mp = M + (size_t)b * SEQ;
    float*       Op = O + base + (size_t)j * 128 * DIM;

    const int tid  = threadIdx.x;
    const int wv   = tid >> 6;     // wave 0..7, owns queries [16wv, 16wv+16)
    const int lane = tid & 63;
    const int lo   = lane & 15;
    const int hi   = lane >> 4;

    __shared__ unsigned short Ks[256][72];        // K window, bf16, padded
    __shared__ unsigned short Vt[64][264];        // V window transposed [d][key], padded
    __shared__ float          Mk[256];            // mask values for window keys
    __shared__ unsigned short Pw[8][2][16][72];   // per-wave P quarter, parity dbuf

    // ---- Q fragments (A-operand, scaled by 1/sqrt(64)=0.125), held in regs ----
    short8 qa[2];
    {
        const float* qr = Qp + (size_t)(wv * 16 + lo) * DIM + hi * 8;
        #pragma unroll
        for (int s = 0; s < 2; ++s) {
            f32x4 a = *reinterpret_cast<const f32x4*>(qr + 32 * s);
            f32x4 c = *reinterpret_cast<const f32x4*>(qr + 32 * s + 4);
            short8 t;
            t[0] = (short)f2bf(a[0] * 0.125f);
            t[1] = (short)f2bf(a[1] * 0.125f);
            t[2] = (short)f2bf(a[2] * 0.125f);
            t[3] = (short)f2bf(a[3] * 0.125f);
            t[4] = (short)f2bf(c[0] * 0.125f);
            t[5] = (short)f2bf(c[1] * 0.125f);
            t[6] = (short)f2bf(c[2] * 0.125f);
            t[7] = (short)f2bf(c[3] * 0.125f);
            qa[s] = t;
        }
    }

    // ---- window list ----
    int nw, wb0, wb1; float wt;
    if (j == 0)       { nw = 1; wb0 = 0;              wb1 = 0;       wt = 1.0f; }
    else if (j == 31) { nw = 1; wb0 = 128 * 31 - 128; wb1 = 0;       wt = 1.0f; }
    else              { nw = 2; wb0 = 128 * j - 128;  wb1 = 128 * j; wt = 0.5f; }

    f32x4 fin[4];
    #pragma unroll
    for (int dt = 0; dt < 4; ++dt) { fin[dt][0]=0.f; fin[dt][1]=0.f; fin[dt][2]=0.f; fin[dt][3]=0.f; }

    for (int w = 0; w < nw; ++w) {
        const int kb = (w == 0) ? wb0 : wb1;

        __syncthreads();   // previous window's reads done before restaging
        // ---- stage K (row-major bf16) and V (transposed bf16) ----
        {
            const int r0 = tid >> 4;          // 0..31
            const int c4 = (tid & 15) * 4;    // 0..60
            #pragma unroll
            for (int rr = 0; rr < 8; ++rr) {
                const int row = r0 + 32 * rr;
                f32x4 kv = *reinterpret_cast<const f32x4*>(Kp + (size_t)(kb + row) * DIM + c4);
                ushort4v kk;
                kk[0] = f2bf(kv[0]); kk[1] = f2bf(kv[1]); kk[2] = f2bf(kv[2]); kk[3] = f2bf(kv[3]);
                *reinterpret_cast<ushort4v*>(&Ks[row][c4]) = kk;
                f32x4 vv = *reinterpret_cast<const f32x4*>(Vp + (size_t)(kb + row) * DIM + c4);
                Vt[c4 + 0][row] = f2bf(vv[0]);
                Vt[c4 + 1][row] = f2bf(vv[1]);
                Vt[c4 + 2][row] = f2bf(vv[2]);
                Vt[c4 + 3][row] = f2bf(vv[3]);
            }
            if (tid < 256) Mk[tid] = Mp[kb + tid];
        }
        __syncthreads();

        // ---- QK^T: scores for wave's 16 rows x 256 keys ----
        f32x4 st[16];
        #pragma unroll
        for (int t = 0; t < 16; ++t) { st[t][0]=0.f; st[t][1]=0.f; st[t][2]=0.f; st[t][3]=0.f; }
        #pragma unroll
        for (int s = 0; s < 2; ++s) {
            #pragma unroll
            for (int t = 0; t < 16; ++t) {
                short8 kf = *reinterpret_cast<const short8*>(&Ks[t * 16 + lo][s * 32 + hi * 8]);
                st[t] = __builtin_amdgcn_mfma_f32_16x16x32_bf16(qa[s], kf, st[t], 0, 0, 0);
            }
        }
        // additive mask (per key, same for all rows)
        #pragma unroll
        for (int t = 0; t < 16; ++t) {
            const float mv = Mk[t * 16 + lo];
            #pragma unroll
            for (int r = 0; r < 4; ++r) st[t][r] += mv;
        }

        // ---- softmax over 256 keys (rows 4*hi+r; cols spread over 16-lane group) ----
        float mx[4], dn[4];
        #pragma unroll
        for (int r = 0; r < 4; ++r) {
            float m = st[0][r];
            #pragma unroll
            for (int t = 1; t < 16; ++t) m = fmaxf(m, st[t][r]);
            m = fmaxf(m, __shfl_xor(m, 1));
            m = fmaxf(m, __shfl_xor(m, 2));
            m = fmaxf(m, __shfl_xor(m, 4));
            m = fmaxf(m, __shfl_xor(m, 8));
            mx[r] = m;
            dn[r] = 0.f;
        }
        #pragma unroll
        for (int t = 0; t < 16; ++t) {
            #pragma unroll
            for (int r = 0; r < 4; ++r) {
                const float p = __expf(st[t][r] - mx[r]);
                st[t][r] = p;
                dn[r] += p;
            }
        }
        #pragma unroll
        for (int r = 0; r < 4; ++r) {
            dn[r] += __shfl_xor(dn[r], 1);
            dn[r] += __shfl_xor(dn[r], 2);
            dn[r] += __shfl_xor(dn[r], 4);
            dn[r] += __shfl_xor(dn[r], 8);
        }

        // ---- PV in 4 quarters of 64 keys (P transposed via per-wave LDS) ----
        f32x4 ow[4];
        #pragma unroll
        for (int dt = 0; dt < 4; ++dt) { ow[dt][0]=0.f; ow[dt][1]=0.f; ow[dt][2]=0.f; ow[dt][3]=0.f; }

        for (int kq = 0; kq < 4; ++kq) {
            const int pb = kq & 1;
            #pragma unroll
            for (int tt = 0; tt < 4; ++tt) {
                const int t = 4 * kq + tt;
                #pragma unroll
                for (int r = 0; r < 4; ++r)
                    Pw[wv][pb][4 * hi + r][tt * 16 + lo] = f2bf(st[t][r]);
            }
            asm volatile("s_waitcnt lgkmcnt(0)" ::: "memory");
            #pragma unroll
            for (int s = 0; s < 2; ++s) {
                short8 pf = *reinterpret_cast<const short8*>(&Pw[wv][pb][lo][s * 32 + hi * 8]);
                #pragma unroll
                for (int dt = 0; dt < 4; ++dt) {
                    short8 vf = *reinterpret_cast<const short8*>(&Vt[dt * 16 + lo][kq * 64 + s * 32 + hi * 8]);
                    ow[dt] = __builtin_amdgcn_mfma_f32_16x16x32_bf16(pf, vf, ow[dt], 0, 0, 0);
                }
            }
        }

        // ---- accumulate weighted, softmax-normalized ----
        float rs[4];
        #pragma unroll
        for (int r = 0; r < 4; ++r) rs[r] = wt / dn[r];
        #pragma unroll
        for (int dt = 0; dt < 4; ++dt)
            #pragma unroll
            for (int r = 0; r < 4; ++r)
                fin[dt][r] += ow[dt][r] * rs[r];
    }

    // ---- write output (fp32, coalesced 64B per 16-lane group) ----
    #pragma unroll
    for (int dt = 0; dt < 4; ++dt)
        #pragma unroll
        for (int r = 0; r < 4; ++r)
            Op[(size_t)(wv * 16 + hi * 4 + r) * DIM + dt * 16 + lo] = fin[dt][r];
}

extern "C" void kernel_launch(void* const* d_in, const int* in_sizes, int n_in,
                              void* d_out, int out_size, void* d_ws, size_t ws_size,
                              hipStream_t stream) {
    const float* Q = (const float*)d_in[0];
    const float* K = (const float*)d_in[1];
    const float* V = (const float*)d_in[2];
    const float* M = (const float*)d_in[3];
    float* O = (float*)d_out;
    blk_attn<<<dim3(NB * NH * (SEQ / 128)), dim3(512), 0, stream>>>(Q, K, V, M, O);
}